// Round 14
// baseline (2745.055 us; speedup 1.0000x reference)
//
#include <hip/hip_runtime.h>
#include <math.h>

typedef __attribute__((ext_vector_type(8))) short short8;
typedef __attribute__((ext_vector_type(4))) float f32x4;

#define NB 64
#define NS 128
#define NE 512
#define NH 512
#define NPOI_ 8192
#define NCAT_ 400
#define NF_ 128
#define H3 1536
#define NEGV -1000000000.0
#define GSZ 32
#define NWG_LAUNCH 256
#define LDT 88
#define NTILES (64*68)

// ws layout (bytes)
#define XF_OFF    0u
#define XB_OFF    16777216u
#define WHH_OFF   25165824u
#define WH1_OFF   26738688u
#define WH2_OFF   26804224u
#define AL_OFF    26871808u
#define IDX_OFF   26937344u
#define GH0_OFF   26970112u
#define CTRL_OFF  26976256u
#define WPOI_OFF  26984448u
#define WCAT_OFF  35373056u
#define GI_OFF    35782656u
#define WS_NEED   86114304u
#define XB2_OFF   86114304u
#define WS_NEED2  94502912u

__device__ inline float sigmf(float x){ return 1.0f/(1.0f + expf(-x)); }
__device__ inline unsigned short f2bf(float f){
    unsigned u = __float_as_uint(f);
    unsigned r = (u + 0x7fffu + ((u>>16)&1u)) >> 16;
    return (unsigned short)r;
}
__device__ inline float bf2f(unsigned short b){ return __uint_as_float(((unsigned)b)<<16); }

// XCD-L2 load (scan-local data)
#define LD16C(d, p, o) asm volatile("global_load_dwordx4 %0, %1, off offset:" o " sc0" : "=&v"(d) : "v"(p))
// coherence-point load (cross-XCD consumer)
#define LD16G(d, p) asm volatile("global_load_dwordx4 %0, %1, off sc0 sc1" : "=&v"(d) : "v"(p))

// ---------- merged init: ctrl clear + all f32->bf16 conversions ----------
__global__ void k_init(int* ctrl,
        const float* __restrict__ s0, unsigned short* __restrict__ d0,
        const float* __restrict__ s1, unsigned short* __restrict__ d1,
        const float* __restrict__ s2, unsigned short* __restrict__ d2,
        const float* __restrict__ s3, unsigned short* __restrict__ d3,
        const float* __restrict__ s4, unsigned short* __restrict__ d4){
    if (blockIdx.x == 0){
        for (int t = threadIdx.x; t < 2048; t += blockDim.x) ctrl[t] = 0;
        __syncthreads();
        if (threadIdx.x == 0) ctrl[9] = -1;
    }
    const int Q0=1048576, Q1=196608, Q2=196608, Q3=1048576, Q4=51200;
    const int total = Q0+Q1+Q2+Q3+Q4;
    for (int q = blockIdx.x*blockDim.x + threadIdx.x; q < total; q += gridDim.x*blockDim.x){
        const float* sp; unsigned short* dp; int o;
        if (q < Q0){ sp=s0; dp=d0; o=q; }
        else if (q < Q0+Q1){ sp=s1; dp=d1; o=q-Q0; }
        else if (q < Q0+Q1+Q2){ sp=s2; dp=d2; o=q-Q0-Q1; }
        else if (q < Q0+Q1+Q2+Q3){ sp=s3; dp=d3; o=q-Q0-Q1-Q2; }
        else { sp=s4; dp=d4; o=q-Q0-Q1-Q2-Q3; }
        float4 v = *(const float4*)(sp + (size_t)o*4);
        ushort4 u;
        u.x=f2bf(v.x); u.y=f2bf(v.y); u.z=f2bf(v.z); u.w=f2bf(v.w);
        *(ushort4*)(dp + (size_t)o*4) = u;
    }
}

// ---------- merged: c1/c2 (per-block, f64) + wh + gh0 ----------
__global__ void k_wh(const float* __restrict__ X, const float* __restrict__ W_attn,
                     const float* __restrict__ a_attn, double* __restrict__ wh1,
                     double* __restrict__ wh2, const float* __restrict__ h0,
                     const float* __restrict__ W_hh, const float* __restrict__ b_hh,
                     float* __restrict__ gh0){
    int blk = blockIdx.x, tid = threadIdx.x;
    if (blk >= 32){
        int c = (blk-32)*256 + tid;
        if (c < H3){
            const float* w = W_hh + (size_t)c*NH;
            float s=0.f;
            for (int k=0;k<NH;k++) s += h0[k]*w[k];
            gh0[c] = s + b_hh[c];
        }
        return;
    }
    __shared__ double c1s[128], c2s[128];
    if (tid < 128){
        double s1=0.0, s2=0.0;
        for (int k=0;k<NF_;k++){
            double w = (double)W_attn[tid*NF_+k];
            s1 += w*(double)a_attn[k];
            s2 += w*(double)a_attn[NF_+k];
        }
        c1s[tid]=s1; c2s[tid]=s2;
    }
    __syncthreads();
    int p = blk*256 + tid;
    const float* x = X + (size_t)p*NF_;
    double s1=0.0, s2=0.0;
    for (int k=0;k<NF_;k++){ double xv=(double)x[k]; s1+=xv*c1s[k]; s2+=xv*c2s[k]; }
    wh1[p]=s1; wh2[p]=s2;
}

__device__ inline double shfl_down_d(double x, int off){
    long long v = __double_as_longlong(x);
    int lo = (int)(v & 0xffffffffLL), hi = (int)(((unsigned long long)v)>>32);
    lo = __shfl_down(lo, off); hi = __shfl_down(hi, off);
    return __longlong_as_double(((long long)hi<<32) | (unsigned long long)(unsigned int)lo);
}

__global__ void k_attn(const int* __restrict__ seq, const int* __restrict__ lens,
                       const float* __restrict__ A, const double* __restrict__ wh1,
                       const double* __restrict__ wh2, float* __restrict__ alpha,
                       int* __restrict__ idxout){
    int gw = (int)((blockIdx.x*(size_t)blockDim.x + threadIdx.x) >> 6);
    int lane = threadIdx.x & 63;
    if (gw >= NB*NS) return;
    int b = gw >> 7, j = gw & 127;
    int len = lens[b];
    int q = seq[b*NS + j];
    double wq = wh2[q];
    bool jvalid = (j < len);
    double mval = -1.0e300; int mk = 0;
    for (int k0=0;k0<NS;k0+=64){
        int k = k0 + lane;
        double val = NEGV;
        if (k < j && jvalid){
            int p = seq[b*NS + k];
            double e = wh1[p] + wq;
            e = (e > 0.0) ? e : 0.2*e;
            val = e * ((double)A[(size_t)p*NPOI_ + q] + 1.0);
        }
        if (val > mval){ mval = val; mk = k; }
    }
    for (int off=32; off; off>>=1){
        double ov = shfl_down_d(mval, off);
        int ok = __shfl_down(mk, off);
        if (ov > mval || (ov == mval && ok < mk)){ mval = ov; mk = ok; }
    }
    if (lane == 0){
        double v0 = mval;
        double v1;
        if (j == 0) v1 = 0.0;
        else if (!jvalid) v1 = NEGV;
        else {
            int p = seq[b*NS + j - 1];
            double e = wh1[p] + wq;
            e = (e > 0.0) ? e : 0.2*e;
            v1 = e * ((double)A[(size_t)p*NPOI_ + q] + 1.0);
        }
        double m = fmax(v0, v1);
        double e0 = exp(v0 - m), e1 = exp(v1 - m);
        double den = e0 + e1;
        alpha[(size_t)(b*NS+j)*2 + 0] = (float)(e0/den);
        alpha[(size_t)(b*NS+j)*2 + 1] = (float)(e1/den);
        idxout[b*NS + j] = mk;
    }
}

// classic NT GEMM (used for gi), XCD-swizzled
__global__ __launch_bounds__(256) void k_gemm_bf16(const unsigned short* __restrict__ A,
        const unsigned short* __restrict__ B, const float* __restrict__ bias,
        float* __restrict__ C, int M, int N, int K, int ldc){
    __shared__ unsigned short As[128][LDT];
    __shared__ unsigned short Bs[128][LDT];
    int nwg = gridDim.x*gridDim.y;
    int lin = blockIdx.y*gridDim.x + blockIdx.x;
    int l2 = (lin & 7)*(nwg >> 3) + (lin >> 3);
    int bm = l2 / gridDim.x, bn = l2 % gridDim.x;
    int row0 = bm*128, col0 = bn*128;
    int tid = threadIdx.x;
    int lane = tid & 63, w = tid >> 6;
    int wr = w >> 1, wc = w & 1;
    int lr = lane & 15, lk = lane >> 4;
    f32x4 acc[4][4] = {};
    for (int k0 = 0; k0 < K; k0 += 64){
        #pragma unroll
        for (int q = 0; q < 4; q++){
            int c = tid + 256*q;
            int r = c >> 3, ko = (c & 7)*8;
            *(short8*)&As[r][ko] = *(const short8*)(A + (size_t)(row0+r)*K + k0 + ko);
            int gc = col0 + r;
            short8 bv = {};
            if (gc < N) bv = *(const short8*)(B + (size_t)gc*K + k0 + ko);
            *(short8*)&Bs[r][ko] = bv;
        }
        __syncthreads();
        #pragma unroll
        for (int ks = 0; ks < 2; ks++){
            int kf = ks*32 + lk*8;
            short8 af[4], bf_[4];
            #pragma unroll
            for (int m=0;m<4;m++) af[m] = *(const short8*)&As[wr*64 + m*16 + lr][kf];
            #pragma unroll
            for (int n=0;n<4;n++) bf_[n] = *(const short8*)&Bs[wc*64 + n*16 + lr][kf];
            #pragma unroll
            for (int m=0;m<4;m++)
                #pragma unroll
                for (int n=0;n<4;n++)
                    acc[m][n] = __builtin_amdgcn_mfma_f32_16x16x32_bf16(af[m], bf_[n], acc[m][n], 0,0,0);
        }
        __syncthreads();
    }
    #pragma unroll
    for (int m=0;m<4;m++){
        #pragma unroll
        for (int n=0;n<4;n++){
            int col = col0 + wc*64 + n*16 + lr;
            if (col < N){
                float bb = bias[col];
                #pragma unroll
                for (int j=0;j<4;j++){
                    int row = row0 + wr*64 + m*16 + lk*4 + j;
                    C[(size_t)row*ldc + col] = acc[m][n][j] + bb;
                }
            }
        }
    }
}

// ---------- mega kernel: pipelined batch-group scan + flag-gated GEMM workers ----------
struct ScanSh {
    float ghs[2][8][16][50];
    unsigned char idx8[NB*NS];
    float bhs[48];
    int s_go, s_rank;
};
struct GemmSh {
    unsigned short As[128][LDT];
    unsigned short Bs[128][LDT];
    int tkt;
};

__global__ __launch_bounds__(512, 2) void k_mega(const float* __restrict__ gi,
        const unsigned short* __restrict__ Whh, const float* __restrict__ bhh,
        const float* __restrict__ alpha, const int* __restrict__ idx,
        const float* __restrict__ gh0, const float* __restrict__ h0v,
        float* __restrict__ xf, unsigned short* __restrict__ xb,
        unsigned short* __restrict__ xb2, int* __restrict__ ctrl,
        const unsigned short* __restrict__ Wpoi, const float* __restrict__ bpoi,
        const unsigned short* __restrict__ Wcat, const float* __restrict__ bcat,
        float* __restrict__ out_poi, float* __restrict__ out_cat, int overlap){
    __shared__ union { ScanSh S; GemmSh G; } U;
    const int tid = threadIdx.x;
    const int lane = tid & 63, w = tid >> 6;
    int* const flagbase = ctrl + 256;
    int* const progp = ctrl + 128;     // progress mirror (counts drained group-flags, 0..1024)

    // ---- election ----
    if (tid == 0){
        int x;
        asm volatile("s_getreg_b32 %0, hwreg(HW_REG_XCC_ID)" : "=s"(x));
        x &= 7;
        int r = __hip_atomic_fetch_add(&ctrl[x], 1, __ATOMIC_RELAXED, __HIP_MEMORY_SCOPE_AGENT);
        int go = 0;
        if (r < GSZ){
            if (r == GSZ-1){
                int exp = -1;
                __hip_atomic_compare_exchange_strong(&ctrl[9], &exp, x,
                    __ATOMIC_RELAXED, __ATOMIC_RELAXED, __HIP_MEMORY_SCOPE_AGENT);
            }
            int spins = 0, wn;
            while ((wn = __hip_atomic_load(&ctrl[9], __ATOMIC_RELAXED, __HIP_MEMORY_SCOPE_AGENT)) == -1
                   && spins < (1<<20)){
                spins++;
                __builtin_amdgcn_s_sleep(1);
            }
            go = (wn == x);
        }
        U.S.s_go = go; U.S.s_rank = r;
    }
    __syncthreads();
    const int isScan = U.S.s_go;
    const int g = U.S.s_rank;
    __syncthreads();

    if (!isScan){
        // ================= GEMM worker (polls progress mirror only) =================
        const int wr = w >> 2, wc = w & 3;
        const int lr = lane & 15, lk = lane >> 4;
        const int c0 = tid, c1 = tid + 512;
        const int r0s = c0 >> 3, ko0 = (c0 & 7)*8;
        const int r1s = c1 >> 3, ko1 = (c1 & 7)*8;
        for (;;){
            if (tid == 0)
                U.G.tkt = __hip_atomic_fetch_add(&ctrl[12], 1, __ATOMIC_RELAXED, __HIP_MEMORY_SCOPE_AGENT);
            __syncthreads();
            int t = U.G.tkt;
            if (t >= NTILES) break;
            int m = t / 68, j = t % 68;
            // progress P = drained group-flags; steps <= s fully drained iff P >= 8*(s+1).
            // tile m reads rows s <= 2m+1  =>  need P >= 16m+16 (cap 1024).
            int target = overlap ? ((16*m + 16 < 1024) ? 16*m + 16 : 1024) : 1024;
            const unsigned short* Bw; const float* bias; float* Cc; int ldc, Ncols, Nrows, col0;
            if (j < 64){ Bw = Wpoi; bias = bpoi; Cc = out_poi; ldc = NPOI_; Ncols = NPOI_; Nrows = NPOI_; col0 = j*128; }
            else       { Bw = Wcat; bias = bcat; Cc = out_cat; ldc = NCAT_; Ncols = NCAT_; Nrows = NCAT_; col0 = (j-64)*128; }
            if (tid == 0){
                int spins = 0;
                while (__hip_atomic_load(progp, __ATOMIC_RELAXED, __HIP_MEMORY_SCOPE_AGENT) < target
                       && spins < (1<<22)){
                    spins++;
                    __builtin_amdgcn_s_sleep(4);
                }
            }
            __syncthreads();
            const unsigned short* pa0 = xb2 + ((size_t)((r0s & 63)*128 + 2*m + (r0s >> 6)))*512 + ko0;
            const unsigned short* pa1 = xb2 + ((size_t)((r1s & 63)*128 + 2*m + (r1s >> 6)))*512 + ko1;
            f32x4 acc[4][2] = {};
            for (int k0 = 0; k0 < NH; k0 += 64){
                short8 a0v, a1v, b0v = {}, b1v = {};
                LD16G(a0v, pa0 + k0);
                LD16G(a1v, pa1 + k0);
                if (col0 + r0s < Nrows) b0v = *(const short8*)(Bw + (size_t)(col0 + r0s)*512 + k0 + ko0);
                if (col0 + r1s < Nrows) b1v = *(const short8*)(Bw + (size_t)(col0 + r1s)*512 + k0 + ko1);
                asm volatile("s_waitcnt vmcnt(0)" ::: "memory");
                *(short8*)&U.G.As[r0s][ko0] = a0v;
                *(short8*)&U.G.As[r1s][ko1] = a1v;
                *(short8*)&U.G.Bs[r0s][ko0] = b0v;
                *(short8*)&U.G.Bs[r1s][ko1] = b1v;
                __syncthreads();
                #pragma unroll
                for (int ks = 0; ks < 2; ks++){
                    int kf = ks*32 + lk*8;
                    short8 af[4], bfr[2];
                    #pragma unroll
                    for (int mi=0;mi<4;mi++) af[mi] = *(const short8*)&U.G.As[wr*64 + mi*16 + lr][kf];
                    #pragma unroll
                    for (int ni=0;ni<2;ni++) bfr[ni] = *(const short8*)&U.G.Bs[wc*32 + ni*16 + lr][kf];
                    #pragma unroll
                    for (int mi=0;mi<4;mi++)
                        #pragma unroll
                        for (int ni=0;ni<2;ni++)
                            acc[mi][ni] = __builtin_amdgcn_mfma_f32_16x16x32_bf16(af[mi], bfr[ni], acc[mi][ni], 0,0,0);
                }
                __syncthreads();
            }
            #pragma unroll
            for (int mi=0;mi<4;mi++){
                #pragma unroll
                for (int ni=0;ni<2;ni++){
                    int col = col0 + wc*32 + ni*16 + lr;
                    if (col < Ncols){
                        float bb = bias[col];
                        #pragma unroll
                        for (int jj=0;jj<4;jj++){
                            int rt = wr*64 + mi*16 + lk*4 + jj;
                            int row = (rt & 63)*128 + 2*m + (rt >> 6);
                            Cc[(size_t)row*ldc + col] = acc[mi][ni][jj] + bb;
                        }
                    }
                }
            }
        }
        return;
    }

    // ================= pipelined scan: 8 batch-groups of 8, rotating fusion wave =================
    // flags: F after (step i, group gq) = i*8+gq+1 (step0 counts +8). Signal is posted one
    // group-step late, AFTER vmcnt(0) => F counts fully-drained group-stores (sc0 and sc1).
    // Gate before (i,gq): all wgs' F >= (i-1)*8+gq+1 = t-7 (t = i*8+gq).
    int* const myflag = flagbase + g*32;
    const int kh = w;                       // K-slice [kh*64, kh*64+64)
    const int lrX = lane & 15, lkX = lane >> 4;

    short8 bwv[3][2];
    {
        const unsigned short* wb = Whh + ((size_t)(g*16 + lrX))*NH + kh*64 + lkX*8;
        #pragma unroll
        for (int gate=0; gate<3; gate++)
            #pragma unroll
            for (int kc=0; kc<2; kc++)
                bwv[gate][kc] = *(const short8*)(wb + gate*262144 + kc*32);
    }
    if (tid < 48) U.S.bhs[tid] = bhh[(tid>>4)*512 + g*16 + (tid&15)];
    for (int c = tid; c < NB*NS; c += 512) U.S.idx8[c] = (unsigned char)idx[c];

    // step 0 (folded): dual store; drain via syncthreads; tid0 signals +8
    for (int e = tid; e < NB*16; e += 512){
        int b = e >> 4, h = g*16 + (e & 15);
        const float* gr = gi + (size_t)b*NS*H3;
        float rr = sigmf(gr[h] + gh0[h]);
        float zz = sigmf(gr[512+h] + gh0[512+h]);
        float nn = tanhf(gr[1024+h] + rr*gh0[1024+h]);
        float v = (1.f-zz)*nn + zz*h0v[h];
        xf[(size_t)b*NS*NH + h] = v;
        unsigned short pv = f2bf(v);
        unsigned short* xa  = xb  + (size_t)b*NS*NH + h;
        unsigned short* xa2 = xb2 + (size_t)b*NS*NH + h;
        asm volatile("global_store_short %0, %1, off sc0" :: "v"(xa), "v"(pv) : "memory");
        asm volatile("global_store_short %0, %1, off sc0 sc1" :: "v"(xa2), "v"(pv) : "memory");
    }
    asm volatile("s_waitcnt vmcnt(0)" ::: "memory");
    __syncthreads();
    if (tid == 0)
        __hip_atomic_fetch_add(myflag, 8, __ATOMIC_RELAXED, __HIP_MEMORY_SCOPE_AGENT);

    int* const pollp = flagbase + (lane & 31)*32;
    const bool isw0g0 = (g == 0 && w == 0);
    int cv = 0;          // per-lane cached flag snapshot
    int lastpub = 0;     // wg0w0 progress publication state
    bool pend = false;

    for (int t = 8; t < 1024; t++){
        const int i = t >> 3, gq = t & 7;
        const int par = t & 1;
        // ---- pending signal (drain THIS wave's fusion stores first) ----
        if (pend){
            asm volatile("s_waitcnt vmcnt(0)" ::: "memory");
            if (lane == 0)
                __hip_atomic_fetch_add(myflag, 1, __ATOMIC_RELAXED, __HIP_MEMORY_SCOPE_AGENT);
            pend = false;
        }
        // ---- gate: need all flags >= t-7 (poll only when cached snapshot is stale) ----
        {
            int need = t - 7;
            if (!__all(cv >= need)){
                int spins = 0;
                do {
                    cv = __hip_atomic_load(pollp, __ATOMIC_RELAXED, __HIP_MEMORY_SCOPE_AGENT);
                    if (isw0g0){
                        int mn = cv;
                        #pragma unroll
                        for (int off=32; off; off>>=1){
                            int o = __shfl_down(mn, off);
                            mn = (o < mn) ? o : mn;
                        }
                        if (lane == 0 && mn > lastpub){
                            __hip_atomic_fetch_add(progp, mn - lastpub, __ATOMIC_RELAXED, __HIP_MEMORY_SCOPE_AGENT);
                            lastpub = mn;
                        }
                    }
                } while (!__all(cv >= need) && ++spins < (1<<20));
            }
        }
        // ---- A-loads for this group: M=16 rows (8 batches x 2 variants), my K-slice ----
        {
            int bA = gq*8 + (lrX & 7);
            int sr = (lrX >> 3) ? (int)U.S.idx8[bA*NS + i] : (i-1);
            const unsigned short* ap = xb + ((size_t)(bA*NS + sr))*NH + kh*64 + lkX*8;
            short8 aA0, aA1;
            LD16C(aA0, ap, "0");
            LD16C(aA1, ap, "64");
            asm volatile("s_waitcnt vmcnt(0)" ::: "memory");
            __builtin_amdgcn_sched_barrier(0);
            f32x4 acc0 = {}, acc1 = {}, acc2 = {};
            acc0 = __builtin_amdgcn_mfma_f32_16x16x32_bf16(aA0, bwv[0][0], acc0, 0,0,0);
            acc1 = __builtin_amdgcn_mfma_f32_16x16x32_bf16(aA0, bwv[1][0], acc1, 0,0,0);
            acc2 = __builtin_amdgcn_mfma_f32_16x16x32_bf16(aA0, bwv[2][0], acc2, 0,0,0);
            acc0 = __builtin_amdgcn_mfma_f32_16x16x32_bf16(aA1, bwv[0][1], acc0, 0,0,0);
            acc1 = __builtin_amdgcn_mfma_f32_16x16x32_bf16(aA1, bwv[1][1], acc1, 0,0,0);
            acc2 = __builtin_amdgcn_mfma_f32_16x16x32_bf16(aA1, bwv[2][1], acc2, 0,0,0);
            #pragma unroll
            for (int j=0;j<4;j++){
                int mr = lkX*4 + j;
                U.S.ghs[par][kh][mr][lrX]      = acc0[j];
                U.S.ghs[par][kh][mr][16+lrX]   = acc1[j];
                U.S.ghs[par][kh][mr][32+lrX]   = acc2[j];
            }
        }
        __syncthreads();
        // ---- rotating fusion wave: reduce 8 partials, gates, dual-store, mark pending ----
        if (w == (t & 7)){
            int hp = lane & 15;
            #pragma unroll
            for (int u=0; u<2; u++){
                int b_l = u*4 + (lane >> 4);
                int b = gq*8 + b_l;
                int h = g*16 + hp;
                int rid = U.S.idx8[b*NS + i];
                const float* gr = gi + ((size_t)b*NS + i)*H3 + h;
                float irv = gr[0], izv = gr[512], innv = gr[1024];
                float2 av = *(const float2*)(alpha + ((size_t)b*NS + i)*2);
                float h1p = xf[((size_t)b*NS + i-1)*NH + h];
                float h2p = xf[((size_t)b*NS + rid)*NH + h];
                float g1r = U.S.bhs[hp], g1z = U.S.bhs[16+hp], g1n = U.S.bhs[32+hp];
                float g2r = g1r, g2z = g1z, g2n = g1n;
                #pragma unroll
                for (int p=0;p<8;p++){
                    g1r += U.S.ghs[par][p][b_l][hp];
                    g1z += U.S.ghs[par][p][b_l][16+hp];
                    g1n += U.S.ghs[par][p][b_l][32+hp];
                    g2r += U.S.ghs[par][p][8+b_l][hp];
                    g2z += U.S.ghs[par][p][8+b_l][16+hp];
                    g2n += U.S.ghs[par][p][8+b_l][32+hp];
                }
                float r1v = sigmf(irv + g1r), z1 = sigmf(izv + g1z);
                float n1 = tanhf(innv + r1v*g1n);
                float hid1 = (1.f-z1)*n1 + z1*h1p;
                float r2v = sigmf(irv + g2r), z2 = sigmf(izv + g2z);
                float n2 = tanhf(innv + r2v*g2n);
                float hid2 = (1.f-z2)*n2 + z2*h2p;
                float v = av.x*hid1 + av.y*hid2;
                xf[((size_t)b*NS + i)*NH + h] = v;
                unsigned short pv = f2bf(v);
                unsigned short* xa  = xb  + ((size_t)b*NS + i)*NH + h;
                unsigned short* xa2 = xb2 + ((size_t)b*NS + i)*NH + h;
                asm volatile("global_store_short %0, %1, off sc0" :: "v"(xa), "v"(pv) : "memory");
                asm volatile("global_store_short %0, %1, off sc0 sc1" :: "v"(xa2), "v"(pv) : "memory");
            }
            pend = true;
        }
    }
    // final pending signals + progress completion
    if (pend){
        asm volatile("s_waitcnt vmcnt(0)" ::: "memory");
        if (lane == 0)
            __hip_atomic_fetch_add(myflag, 1, __ATOMIC_RELAXED, __HIP_MEMORY_SCOPE_AGENT);
        pend = false;
    }
    if (isw0g0){
        int spins = 0;
        while (1){
            cv = __hip_atomic_load(pollp, __ATOMIC_RELAXED, __HIP_MEMORY_SCOPE_AGENT);
            if (__all(cv >= 1024)) break;
            if (++spins > (1<<20)) break;
            __builtin_amdgcn_s_sleep(1);
        }
        if (lane == 0 && lastpub < 1024)
            __hip_atomic_fetch_add(progp, 1024 - lastpub, __ATOMIC_RELAXED, __HIP_MEMORY_SCOPE_AGENT);
    }
}

// out_time: wave per row (reads f32 state)
__global__ void k_time(const float* __restrict__ xf, const float* __restrict__ W_time,
                       const float* __restrict__ b_time, float* __restrict__ out){
    int gw = (int)((blockIdx.x*(size_t)blockDim.x + threadIdx.x) >> 6);
    int lane = threadIdx.x & 63;
    if (gw >= NB*NS) return;
    const float* x = xf + (size_t)gw*NH;
    float s = 0.f;
    for (int k=lane;k<NH;k+=64) s += x[k]*W_time[k];
    for (int off=32; off; off>>=1) s += __shfl_down(s, off);
    if (lane == 0) out[gw] = s + b_time[0];
}

extern "C" void kernel_launch(void* const* d_in, const int* in_sizes, int n_in,
                              void* d_out, int out_size, void* d_ws, size_t ws_size,
                              hipStream_t stream){
    const float* src    = (const float*)d_in[0];
    const int*   lens   = (const int*)d_in[1];
    const int*   seq    = (const int*)d_in[2];
    const float* X      = (const float*)d_in[3];
    const float* A      = (const float*)d_in[4];
    const float* W_attn = (const float*)d_in[5];
    const float* a_attn = (const float*)d_in[6];
    const float* W_ih   = (const float*)d_in[7];
    const float* W_hh   = (const float*)d_in[8];
    const float* b_ih   = (const float*)d_in[9];
    const float* b_hh   = (const float*)d_in[10];
    const float* h0     = (const float*)d_in[11];
    const float* W_poi  = (const float*)d_in[12];
    const float* b_poi  = (const float*)d_in[13];
    const float* W_time = (const float*)d_in[14];
    const float* b_time = (const float*)d_in[15];
    const float* W_cat  = (const float*)d_in[16];
    const float* b_cat  = (const float*)d_in[17];

    char* ws = (char*)d_ws;
    float*          xf      = (float*)(ws + XF_OFF);
    unsigned short* xb      = (unsigned short*)(ws + XB_OFF);
    unsigned short* Whh_bf  = (unsigned short*)(ws + WHH_OFF);
    double*         wh1     = (double*)(ws + WH1_OFF);
    double*         wh2     = (double*)(ws + WH2_OFF);
    float*          alpha   = (float*)(ws + AL_OFF);
    int*            idx     = (int*)(ws + IDX_OFF);
    float*          gh0     = (float*)(ws + GH0_OFF);
    int*            ctrl    = (int*)(ws + CTRL_OFF);
    unsigned short* Wpoi_bf = (unsigned short*)(ws + WPOI_OFF);
    unsigned short* Wcat_bf = (unsigned short*)(ws + WCAT_OFF);

    int overlap = (ws_size >= (size_t)WS_NEED) ? 1 : 0;
    unsigned short* xb2 = (ws_size >= (size_t)WS_NEED2) ? (unsigned short*)(ws + XB2_OFF) : xb;

    char* ob = (char*)d_out;
    unsigned short* src_bf = (unsigned short*)(ob + 0);         // dead before C writes
    unsigned short* Wih_bf = (unsigned short*)(ob + 9437184);
    float* gi = overlap ? (float*)(ws + GI_OFF) : (float*)(ob + 16777216);

    float* out_poi  = (float*)d_out;
    float* out_time = (float*)d_out + (size_t)8192*8192;
    float* out_cat  = out_time + 8192;

    k_init<<<4096, 256, 0, stream>>>(ctrl, src, src_bf, W_ih, Wih_bf, W_hh, Whh_bf,
                                     W_poi, Wpoi_bf, W_cat, Wcat_bf);
    k_wh<<<38, 256, 0, stream>>>(X, W_attn, a_attn, wh1, wh2, h0, W_hh, b_hh, gh0);
    k_attn<<<2048, 256, 0, stream>>>(seq, lens, A, wh1, wh2, alpha, idx);

    k_gemm_bf16<<<dim3(12, 64), 256, 0, stream>>>(src_bf, Wih_bf, b_ih, gi, NB*NS, H3, NE, H3);

    k_mega<<<NWG_LAUNCH, 512, 0, stream>>>(gi, Whh_bf, b_hh, alpha, idx, gh0, h0,
                                           xf, xb, xb2, ctrl, Wpoi_bf, b_poi, Wcat_bf, b_cat,
                                           out_poi, out_cat, overlap);

    k_time<<<2048, 256, 0, stream>>>(xf, W_time, b_time, out_time);
}

// Round 15
// 955.723 us; speedup vs baseline: 2.8722x; 2.8722x over previous
//
#include <hip/hip_runtime.h>
#include <math.h>

typedef __attribute__((ext_vector_type(8))) short short8;
typedef __attribute__((ext_vector_type(4))) float f32x4;

#define NB 64
#define NS 128
#define NE 512
#define NH 512
#define NPOI_ 8192
#define NCAT_ 400
#define NF_ 128
#define H3 1536
#define NEGV -1000000000.0
#define GSZ 32
#define NWG_LAUNCH 256
#define LDT 88
#define NTILES (64*68)

// ws layout (bytes)
#define XF_OFF    0u
#define XB_OFF    16777216u
#define WHH_OFF   25165824u
#define WH1_OFF   26738688u
#define WH2_OFF   26804224u
#define AL_OFF    26871808u
#define IDX_OFF   26937344u
#define GH0_OFF   26970112u
#define CTRL_OFF  26976256u
#define WPOI_OFF  26984448u
#define WCAT_OFF  35373056u
#define GI_OFF    35782656u
#define WS_NEED   86114304u
#define XB2_OFF   86114304u
#define WS_NEED2  94502912u

__device__ inline float sigmf(float x){ return 1.0f/(1.0f + expf(-x)); }
__device__ inline unsigned short f2bf(float f){
    unsigned u = __float_as_uint(f);
    unsigned r = (u + 0x7fffu + ((u>>16)&1u)) >> 16;
    return (unsigned short)r;
}
__device__ inline float bf2f(unsigned short b){ return __uint_as_float(((unsigned)b)<<16); }

// XCD-L2 load (scan-local data)
#define LD16C(d, p, o) asm volatile("global_load_dwordx4 %0, %1, off offset:" o " sc0" : "=&v"(d) : "v"(p))
// coherence-point load (cross-XCD consumer)
#define LD16G(d, p) asm volatile("global_load_dwordx4 %0, %1, off sc0 sc1" : "=&v"(d) : "v"(p))

// ---------- merged init: ctrl clear + wh/gh0 + all f32->bf16 conversions ----------
__global__ void k_init(int* ctrl,
        const float* __restrict__ s0, unsigned short* __restrict__ d0,
        const float* __restrict__ s1, unsigned short* __restrict__ d1,
        const float* __restrict__ s2, unsigned short* __restrict__ d2,
        const float* __restrict__ s3, unsigned short* __restrict__ d3,
        const float* __restrict__ s4, unsigned short* __restrict__ d4,
        const float* __restrict__ X, const float* __restrict__ W_attn,
        const float* __restrict__ a_attn, double* __restrict__ wh1,
        double* __restrict__ wh2, const float* __restrict__ h0,
        const float* __restrict__ W_hh_f, const float* __restrict__ b_hh,
        float* __restrict__ gh0){
    int blk = blockIdx.x, tid = threadIdx.x;
    if (blk == 0){
        for (int t = tid; t < 2048; t += blockDim.x) ctrl[t] = 0;
        __syncthreads();
        if (tid == 0) ctrl[9] = -1;
    } else if (blk <= 32){
        __shared__ double c1s[128], c2s[128];
        if (tid < 128){
            double sa=0.0, sb=0.0;
            for (int k=0;k<NF_;k++){
                double w = (double)W_attn[tid*NF_+k];
                sa += w*(double)a_attn[k];
                sb += w*(double)a_attn[NF_+k];
            }
            c1s[tid]=sa; c2s[tid]=sb;
        }
        __syncthreads();
        int p = (blk-1)*256 + tid;
        const float* x = X + (size_t)p*NF_;
        double sa=0.0, sb=0.0;
        for (int k=0;k<NF_;k++){ double xv=(double)x[k]; sa+=xv*c1s[k]; sb+=xv*c2s[k]; }
        wh1[p]=sa; wh2[p]=sb;
    } else if (blk <= 38){
        int c = (blk-33)*256 + tid;
        if (c < H3){
            const float* w = W_hh_f + (size_t)c*NH;
            float s=0.f;
            for (int k=0;k<NH;k++) s += h0[k]*w[k];
            gh0[c] = s + b_hh[c];
        }
    }
    const int Q0=1048576, Q1=196608, Q2=196608, Q3=1048576, Q4=51200;
    const int total = Q0+Q1+Q2+Q3+Q4;
    for (int q = blk*blockDim.x + tid; q < total; q += gridDim.x*blockDim.x){
        const float* sp; unsigned short* dp; int o;
        if (q < Q0){ sp=s0; dp=d0; o=q; }
        else if (q < Q0+Q1){ sp=s1; dp=d1; o=q-Q0; }
        else if (q < Q0+Q1+Q2){ sp=s2; dp=d2; o=q-Q0-Q1; }
        else if (q < Q0+Q1+Q2+Q3){ sp=s3; dp=d3; o=q-Q0-Q1-Q2; }
        else { sp=s4; dp=d4; o=q-Q0-Q1-Q2-Q3; }
        float4 v = *(const float4*)(sp + (size_t)o*4);
        ushort4 u;
        u.x=f2bf(v.x); u.y=f2bf(v.y); u.z=f2bf(v.z); u.w=f2bf(v.w);
        *(ushort4*)(dp + (size_t)o*4) = u;
    }
}

__device__ inline double shfl_down_d(double x, int off){
    long long v = __double_as_longlong(x);
    int lo = (int)(v & 0xffffffffLL), hi = (int)(((unsigned long long)v)>>32);
    lo = __shfl_down(lo, off); hi = __shfl_down(hi, off);
    return __longlong_as_double(((long long)hi<<32) | (unsigned long long)(unsigned int)lo);
}

// ---------- merged: gi GEMM (blocks 0..767) + attention scores (blocks 768..2815) ----------
__global__ __launch_bounds__(256) void k_ag(const unsigned short* __restrict__ Ag,
        const unsigned short* __restrict__ Bg, const float* __restrict__ bias,
        float* __restrict__ C,
        const int* __restrict__ seq, const int* __restrict__ lens,
        const float* __restrict__ Aadj, const double* __restrict__ wh1,
        const double* __restrict__ wh2, float* __restrict__ alpha,
        int* __restrict__ idxout){
    if (blockIdx.x < 768){
        // gi = src_bf @ Wih_bf^T + b_ih : M=8192, N=1536, K=512, ldc=1536 (XCD-swizzled)
        __shared__ unsigned short As[128][LDT];
        __shared__ unsigned short Bs[128][LDT];
        int lin = blockIdx.x;
        int l2 = (lin & 7)*96 + (lin >> 3);
        int bm = l2 / 12, bn = l2 % 12;
        int row0 = bm*128, col0 = bn*128;
        int tid = threadIdx.x;
        int lane = tid & 63, w = tid >> 6;
        int wr = w >> 1, wc = w & 1;
        int lr = lane & 15, lk = lane >> 4;
        f32x4 acc[4][4] = {};
        for (int k0 = 0; k0 < NE; k0 += 64){
            #pragma unroll
            for (int q = 0; q < 4; q++){
                int c = tid + 256*q;
                int r = c >> 3, ko = (c & 7)*8;
                *(short8*)&As[r][ko] = *(const short8*)(Ag + (size_t)(row0+r)*NE + k0 + ko);
                *(short8*)&Bs[r][ko] = *(const short8*)(Bg + (size_t)(col0+r)*NE + k0 + ko);
            }
            __syncthreads();
            #pragma unroll
            for (int ks = 0; ks < 2; ks++){
                int kf = ks*32 + lk*8;
                short8 af[4], bf_[4];
                #pragma unroll
                for (int m=0;m<4;m++) af[m] = *(const short8*)&As[wr*64 + m*16 + lr][kf];
                #pragma unroll
                for (int n=0;n<4;n++) bf_[n] = *(const short8*)&Bs[wc*64 + n*16 + lr][kf];
                #pragma unroll
                for (int m=0;m<4;m++)
                    #pragma unroll
                    for (int n=0;n<4;n++)
                        acc[m][n] = __builtin_amdgcn_mfma_f32_16x16x32_bf16(af[m], bf_[n], acc[m][n], 0,0,0);
            }
            __syncthreads();
        }
        #pragma unroll
        for (int m=0;m<4;m++){
            #pragma unroll
            for (int n=0;n<4;n++){
                int col = col0 + wc*64 + n*16 + lr;
                float bb = bias[col];
                #pragma unroll
                for (int j=0;j<4;j++){
                    int row = row0 + wr*64 + m*16 + lk*4 + j;
                    C[(size_t)row*H3 + col] = acc[m][n][j] + bb;
                }
            }
        }
        return;
    }
    // ---- attention: wave per (b,j) ----
    int gw = (int)(((blockIdx.x - 768)*(size_t)blockDim.x + threadIdx.x) >> 6);
    int lane = threadIdx.x & 63;
    if (gw >= NB*NS) return;
    int b = gw >> 7, j = gw & 127;
    int len = lens[b];
    int q = seq[b*NS + j];
    double wq = wh2[q];
    bool jvalid = (j < len);
    double mval = -1.0e300; int mk = 0;
    for (int k0=0;k0<NS;k0+=64){
        int k = k0 + lane;
        double val = NEGV;
        if (k < j && jvalid){
            int p = seq[b*NS + k];
            double e = wh1[p] + wq;
            e = (e > 0.0) ? e : 0.2*e;
            val = e * ((double)Aadj[(size_t)p*NPOI_ + q] + 1.0);
        }
        if (val > mval){ mval = val; mk = k; }
    }
    for (int off=32; off; off>>=1){
        double ov = shfl_down_d(mval, off);
        int ok = __shfl_down(mk, off);
        if (ov > mval || (ov == mval && ok < mk)){ mval = ov; mk = ok; }
    }
    if (lane == 0){
        double v0 = mval;
        double v1;
        if (j == 0) v1 = 0.0;
        else if (!jvalid) v1 = NEGV;
        else {
            int p = seq[b*NS + j - 1];
            double e = wh1[p] + wq;
            e = (e > 0.0) ? e : 0.2*e;
            v1 = e * ((double)Aadj[(size_t)p*NPOI_ + q] + 1.0);
        }
        double m = fmax(v0, v1);
        double e0 = exp(v0 - m), e1 = exp(v1 - m);
        double den = e0 + e1;
        alpha[(size_t)(b*NS+j)*2 + 0] = (float)(e0/den);
        alpha[(size_t)(b*NS+j)*2 + 1] = (float)(e1/den);
        idxout[b*NS + j] = mk;
    }
}

// ---------- mega kernel (r12 structure, verbatim) ----------
struct ScanSh {
    float ghs[2][128][50];
    unsigned char idx8[NB*NS];
    float bhs[48];
    int s_go, s_rank;
};
struct GemmSh {
    unsigned short As[128][LDT];
    unsigned short Bs[128][LDT];
    int tkt;
};

__global__ __launch_bounds__(512, 2) void k_mega(const float* __restrict__ gi,
        const unsigned short* __restrict__ Whh, const float* __restrict__ bhh,
        const float* __restrict__ alpha, const int* __restrict__ idx,
        const float* __restrict__ gh0, const float* __restrict__ h0v,
        float* __restrict__ xf, unsigned short* __restrict__ xb,
        unsigned short* __restrict__ xb2, int* __restrict__ ctrl,
        const unsigned short* __restrict__ Wpoi, const float* __restrict__ bpoi,
        const unsigned short* __restrict__ Wcat, const float* __restrict__ bcat,
        float* __restrict__ out_poi, float* __restrict__ out_cat, int overlap){
    __shared__ union { ScanSh S; GemmSh G; } U;
    const int tid = threadIdx.x;
    const int lane = tid & 63, w = tid >> 6;
    int* const flagbase = ctrl + 256;
    int* const progp = ctrl + 128;

    // ---- election ----
    if (tid == 0){
        int x;
        asm volatile("s_getreg_b32 %0, hwreg(HW_REG_XCC_ID)" : "=s"(x));
        x &= 7;
        int r = __hip_atomic_fetch_add(&ctrl[x], 1, __ATOMIC_RELAXED, __HIP_MEMORY_SCOPE_AGENT);
        int go = 0;
        if (r < GSZ){
            if (r == GSZ-1){
                int exp = -1;
                __hip_atomic_compare_exchange_strong(&ctrl[9], &exp, x,
                    __ATOMIC_RELAXED, __ATOMIC_RELAXED, __HIP_MEMORY_SCOPE_AGENT);
            }
            int spins = 0, wn;
            while ((wn = __hip_atomic_load(&ctrl[9], __ATOMIC_RELAXED, __HIP_MEMORY_SCOPE_AGENT)) == -1
                   && spins < (1<<20)){
                spins++;
                __builtin_amdgcn_s_sleep(1);
            }
            go = (wn == x);
        }
        U.S.s_go = go; U.S.s_rank = r;
    }
    __syncthreads();
    const int isScan = U.S.s_go;
    const int g = U.S.s_rank;
    __syncthreads();

    if (!isScan){
        // ================= GEMM worker (polls progress mirror only) =================
        const int wr = w >> 2, wc = w & 3;
        const int lr = lane & 15, lk = lane >> 4;
        const int c0 = tid, c1 = tid + 512;
        const int r0s = c0 >> 3, ko0 = (c0 & 7)*8;
        const int r1s = c1 >> 3, ko1 = (c1 & 7)*8;
        for (;;){
            if (tid == 0)
                U.G.tkt = __hip_atomic_fetch_add(&ctrl[12], 1, __ATOMIC_RELAXED, __HIP_MEMORY_SCOPE_AGENT);
            __syncthreads();
            int t = U.G.tkt;
            if (t >= NTILES) break;
            int m = t / 68, j = t % 68;
            int target = overlap ? (2*m + 2) : 128;
            const unsigned short* Bw; const float* bias; float* Cc; int ldc, Ncols, Nrows, col0;
            if (j < 64){ Bw = Wpoi; bias = bpoi; Cc = out_poi; ldc = NPOI_; Ncols = NPOI_; Nrows = NPOI_; col0 = j*128; }
            else       { Bw = Wcat; bias = bcat; Cc = out_cat; ldc = NCAT_; Ncols = NCAT_; Nrows = NCAT_; col0 = (j-64)*128; }
            if (tid == 0){
                int spins = 0;
                while (__hip_atomic_load(progp, __ATOMIC_RELAXED, __HIP_MEMORY_SCOPE_AGENT) < target
                       && spins < (1<<22)){
                    spins++;
                    __builtin_amdgcn_s_sleep(4);
                }
            }
            __syncthreads();
            const unsigned short* pa0 = xb2 + ((size_t)((r0s & 63)*128 + 2*m + (r0s >> 6)))*512 + ko0;
            const unsigned short* pa1 = xb2 + ((size_t)((r1s & 63)*128 + 2*m + (r1s >> 6)))*512 + ko1;
            f32x4 acc[4][2] = {};
            for (int k0 = 0; k0 < NH; k0 += 64){
                short8 a0v, a1v, b0v = {}, b1v = {};
                LD16G(a0v, pa0 + k0);
                LD16G(a1v, pa1 + k0);
                if (col0 + r0s < Nrows) b0v = *(const short8*)(Bw + (size_t)(col0 + r0s)*512 + k0 + ko0);
                if (col0 + r1s < Nrows) b1v = *(const short8*)(Bw + (size_t)(col0 + r1s)*512 + k0 + ko1);
                asm volatile("s_waitcnt vmcnt(0)" ::: "memory");
                *(short8*)&U.G.As[r0s][ko0] = a0v;
                *(short8*)&U.G.As[r1s][ko1] = a1v;
                *(short8*)&U.G.Bs[r0s][ko0] = b0v;
                *(short8*)&U.G.Bs[r1s][ko1] = b1v;
                __syncthreads();
                #pragma unroll
                for (int ks = 0; ks < 2; ks++){
                    int kf = ks*32 + lk*8;
                    short8 af[4], bfr[2];
                    #pragma unroll
                    for (int mi=0;mi<4;mi++) af[mi] = *(const short8*)&U.G.As[wr*64 + mi*16 + lr][kf];
                    #pragma unroll
                    for (int ni=0;ni<2;ni++) bfr[ni] = *(const short8*)&U.G.Bs[wc*32 + ni*16 + lr][kf];
                    #pragma unroll
                    for (int mi=0;mi<4;mi++)
                        #pragma unroll
                        for (int ni=0;ni<2;ni++)
                            acc[mi][ni] = __builtin_amdgcn_mfma_f32_16x16x32_bf16(af[mi], bfr[ni], acc[mi][ni], 0,0,0);
                }
                __syncthreads();
            }
            #pragma unroll
            for (int mi=0;mi<4;mi++){
                #pragma unroll
                for (int ni=0;ni<2;ni++){
                    int col = col0 + wc*32 + ni*16 + lr;
                    if (col < Ncols){
                        float bb = bias[col];
                        #pragma unroll
                        for (int jj=0;jj<4;jj++){
                            int rt = wr*64 + mi*16 + lk*4 + jj;
                            int row = (rt & 63)*128 + 2*m + (rt >> 6);
                            Cc[(size_t)row*ldc + col] = acc[mi][ni][jj] + bb;
                        }
                    }
                }
            }
        }
        return;
    }

    // ================= scan =================
    int* const myflag = flagbase + g*32;
    const int kh = w & 1, mgrp = w >> 1;
    const int lr = lane & 15, lk = lane >> 4;

    short8 bw0[8], bw1[8], bw2[8];
    {
        const unsigned short* wb = Whh + ((size_t)(g*16 + lr))*NH + kh*256 + lk*8;
        #pragma unroll
        for (int ks=0; ks<8; ks++){
            bw0[ks] = *(const short8*)(wb + 0*262144 + ks*32);
            bw1[ks] = *(const short8*)(wb + 1*262144 + ks*32);
            bw2[ks] = *(const short8*)(wb + 2*262144 + ks*32);
        }
    }
    if (tid < 48) U.S.bhs[tid] = bhh[(tid>>4)*512 + g*16 + (tid&15)];
    for (int c = tid; c < NB*NS; c += 512) U.S.idx8[c] = (unsigned char)idx[c];

    // step 0 (folded): dual store (local + LLC copy)
    for (int e = tid; e < NB*16; e += 512){
        int b = e >> 4, h = g*16 + (e & 15);
        const float* gr = gi + (size_t)b*NS*H3;
        float rr = sigmf(gr[h] + gh0[h]);
        float zz = sigmf(gr[512+h] + gh0[512+h]);
        float nn = tanhf(gr[1024+h] + rr*gh0[1024+h]);
        float v = (1.f-zz)*nn + zz*h0v[h];
        xf[(size_t)b*NS*NH + h] = v;
        unsigned short pv = f2bf(v);
        unsigned short* xa  = xb  + (size_t)b*NS*NH + h;
        unsigned short* xa2 = xb2 + (size_t)b*NS*NH + h;
        asm volatile("global_store_short %0, %1, off sc0" :: "v"(xa), "v"(pv) : "memory");
        asm volatile("global_store_short %0, %1, off sc0 sc1" :: "v"(xa2), "v"(pv) : "memory");
    }
    asm volatile("s_waitcnt vmcnt(0)" ::: "memory");
    __syncthreads();
    if (tid == 0)
        __hip_atomic_fetch_add(myflag, 1, __ATOMIC_RELAXED, __HIP_MEMORY_SCOPE_AGENT);

    const int gb = tid >> 3, hp = tid & 7;
    const int hg = g*16 + hp*2;
    const int r0 = mgrp*32 + lr, r1 = r0 + 16;
    const int ab0 = r0 & 63, ab1 = r1 & 63;
    const int v0_ = r0 >> 6, v1_ = r1 >> 6;
    const bool pure2 = (mgrp >= 2);
    int* const pollp = flagbase + (lane & 31)*32;

    float2 h1prev;
    {
        const float* gr = gi + (size_t)gb*NS*H3;
        float o[2];
        #pragma unroll
        for (int u=0;u<2;u++){
            int h = hg+u;
            float rr = sigmf(gr[h] + gh0[h]);
            float zz = sigmf(gr[512+h] + gh0[512+h]);
            float nn = tanhf(gr[1024+h] + rr*gh0[1024+h]);
            o[u] = (1.f-zz)*nn + zz*h0v[h];
        }
        h1prev = make_float2(o[0], o[1]);
    }
    float2 nx0 = *(const float2*)(gi + ((size_t)gb*NS + 1)*H3 + hg);
    float2 nx1 = *(const float2*)(gi + ((size_t)gb*NS + 1)*H3 + 512 + hg);
    float2 nx2 = *(const float2*)(gi + ((size_t)gb*NS + 1)*H3 + 1024 + hg);
    float2 nxA = *(const float2*)(alpha + ((size_t)gb*NS + 1)*2);

    bool earlyN = false;
    short8 a0[8], a1[8];

    for (int i = 1; i < NS; i++){
        if (w == 0){
            int spins = 0;
            while (1){
                int v = __hip_atomic_load(pollp, __ATOMIC_RELAXED, __HIP_MEMORY_SCOPE_AGENT);
                if (__all(v >= i)) break;
                if (++spins > (1<<19)) break;
            }
            if (lane == 0 && g == 0)
                __hip_atomic_fetch_add(progp, 1, __ATOMIC_RELAXED, __HIP_MEMORY_SCOPE_AGENT);
        }
        __syncthreads();
        float2 cg0 = nx0, cg1 = nx1, cg2 = nx2, cA = nxA;
        if (!earlyN){
            int s0 = v0_ ? (int)U.S.idx8[ab0*NS + i] : (i-1);
            int s1 = v1_ ? (int)U.S.idx8[ab1*NS + i] : (i-1);
            const unsigned short* ap0 = xb + ((size_t)ab0*NS + s0)*NH + kh*256 + lk*8;
            const unsigned short* ap1 = xb + ((size_t)ab1*NS + s1)*NH + kh*256 + lk*8;
            LD16C(a0[0], ap0, "0");   LD16C(a0[1], ap0, "64");  LD16C(a0[2], ap0, "128"); LD16C(a0[3], ap0, "192");
            LD16C(a0[4], ap0, "256"); LD16C(a0[5], ap0, "320"); LD16C(a0[6], ap0, "384"); LD16C(a0[7], ap0, "448");
            LD16C(a1[0], ap1, "0");   LD16C(a1[1], ap1, "64");  LD16C(a1[2], ap1, "128"); LD16C(a1[3], ap1, "192");
            LD16C(a1[4], ap1, "256"); LD16C(a1[5], ap1, "320"); LD16C(a1[6], ap1, "384"); LD16C(a1[7], ap1, "448");
        }
        asm volatile("s_waitcnt vmcnt(0)" ::: "memory");
        __builtin_amdgcn_sched_barrier(0);
        f32x4 acc00 = {}, acc01 = {}, acc02 = {}, acc10 = {}, acc11 = {}, acc12 = {};
        #pragma unroll
        for (int ks=0; ks<8; ks++){
            acc00 = __builtin_amdgcn_mfma_f32_16x16x32_bf16(a0[ks], bw0[ks], acc00, 0,0,0);
            acc01 = __builtin_amdgcn_mfma_f32_16x16x32_bf16(a0[ks], bw1[ks], acc01, 0,0,0);
            acc02 = __builtin_amdgcn_mfma_f32_16x16x32_bf16(a0[ks], bw2[ks], acc02, 0,0,0);
            acc10 = __builtin_amdgcn_mfma_f32_16x16x32_bf16(a1[ks], bw0[ks], acc10, 0,0,0);
            acc11 = __builtin_amdgcn_mfma_f32_16x16x32_bf16(a1[ks], bw1[ks], acc11, 0,0,0);
            acc12 = __builtin_amdgcn_mfma_f32_16x16x32_bf16(a1[ks], bw2[ks], acc12, 0,0,0);
        }
        {
            int ip = (i+1 < NS) ? (i+1) : (NS-1);
            nx0 = *(const float2*)(gi + ((size_t)gb*NS + ip)*H3 + hg);
            nx1 = *(const float2*)(gi + ((size_t)gb*NS + ip)*H3 + 512 + hg);
            nx2 = *(const float2*)(gi + ((size_t)gb*NS + ip)*H3 + 1024 + hg);
            nxA = *(const float2*)(alpha + ((size_t)gb*NS + ip)*2);
        }
        #pragma unroll
        for (int j=0;j<4;j++){
            int m0 = mgrp*32 + lk*4 + j, m1 = m0 + 16;
            U.S.ghs[kh][m0][lr]    = acc00[j];
            U.S.ghs[kh][m0][16+lr] = acc01[j];
            U.S.ghs[kh][m0][32+lr] = acc02[j];
            U.S.ghs[kh][m1][lr]    = acc10[j];
            U.S.ghs[kh][m1][16+lr] = acc11[j];
            U.S.ghs[kh][m1][32+lr] = acc12[j];
        }
        __syncthreads();
        {
            int rid = U.S.idx8[gb*NS + i];
            float2 h2p = *(const float2*)(xf + ((size_t)gb*NS + rid)*NH + hg);
            float o0, o1;
            #pragma unroll
            for (int u=0; u<2; u++){
                int hl = hp*2 + u;
                float g1r = U.S.ghs[0][gb][hl]       + U.S.ghs[1][gb][hl]       + U.S.bhs[hl];
                float g1z = U.S.ghs[0][gb][16+hl]    + U.S.ghs[1][gb][16+hl]    + U.S.bhs[16+hl];
                float g1n = U.S.ghs[0][gb][32+hl]    + U.S.ghs[1][gb][32+hl]    + U.S.bhs[32+hl];
                float g2r = U.S.ghs[0][64+gb][hl]    + U.S.ghs[1][64+gb][hl]    + U.S.bhs[hl];
                float g2z = U.S.ghs[0][64+gb][16+hl] + U.S.ghs[1][64+gb][16+hl] + U.S.bhs[16+hl];
                float g2n = U.S.ghs[0][64+gb][32+hl] + U.S.ghs[1][64+gb][32+hl] + U.S.bhs[32+hl];
                float ir  = u ? cg0.y : cg0.x;
                float iz  = u ? cg1.y : cg1.x;
                float inn = u ? cg2.y : cg2.x;
                float hh1 = u ? h1prev.y : h1prev.x;
                float hh2 = u ? h2p.y : h2p.x;
                float r1v = sigmf(ir + g1r), z1 = sigmf(iz + g1z);
                float n1 = tanhf(inn + r1v*g1n);
                float hid1 = (1.f-z1)*n1 + z1*hh1;
                float r2v = sigmf(ir + g2r), z2 = sigmf(iz + g2z);
                float n2 = tanhf(inn + r2v*g2n);
                float hid2 = (1.f-z2)*n2 + z2*hh2;
                float v = cA.x*hid1 + cA.y*hid2;
                if (u) o1 = v; else o0 = v;
            }
            *(float2*)(xf + ((size_t)gb*NS + i)*NH + hg) = make_float2(o0, o1);
            unsigned pk = (unsigned)f2bf(o0) | ((unsigned)f2bf(o1) << 16);
            unsigned short* xaddr  = xb  + ((size_t)gb*NS + i)*NH + hg;
            unsigned short* xaddr2 = xb2 + ((size_t)gb*NS + i)*NH + hg;
            asm volatile("global_store_dword %0, %1, off sc0" :: "v"(xaddr), "v"(pk) : "memory");
            asm volatile("global_store_dword %0, %1, off sc0 sc1" :: "v"(xaddr2), "v"(pk) : "memory");
            h1prev = make_float2(o0, o1);
        }
        asm volatile("s_waitcnt vmcnt(0)" ::: "memory");
        __syncthreads();
        if (tid == 0)
            __hip_atomic_fetch_add(myflag, 1, __ATOMIC_RELAXED, __HIP_MEMORY_SCOPE_AGENT);
        earlyN = false;
        if (pure2 && (i+1 < NS)){
            int s0n = (int)U.S.idx8[ab0*NS + i+1];
            int s1n = (int)U.S.idx8[ab1*NS + i+1];
            if (__all((s0n <= i-1) && (s1n <= i-1))){
                earlyN = true;
                const unsigned short* ap0 = xb + ((size_t)ab0*NS + s0n)*NH + kh*256 + lk*8;
                const unsigned short* ap1 = xb + ((size_t)ab1*NS + s1n)*NH + kh*256 + lk*8;
                LD16C(a0[0], ap0, "0");   LD16C(a0[1], ap0, "64");  LD16C(a0[2], ap0, "128"); LD16C(a0[3], ap0, "192");
                LD16C(a0[4], ap0, "256"); LD16C(a0[5], ap0, "320"); LD16C(a0[6], ap0, "384"); LD16C(a0[7], ap0, "448");
                LD16C(a1[0], ap1, "0");   LD16C(a1[1], ap1, "64");  LD16C(a1[2], ap1, "128"); LD16C(a1[3], ap1, "192");
                LD16C(a1[4], ap1, "256"); LD16C(a1[5], ap1, "320"); LD16C(a1[6], ap1, "384"); LD16C(a1[7], ap1, "448");
            }
        }
    }
    // publish final progress after confirming all flags done
    if (g == 0){
        if (w == 0){
            int spins = 0;
            while (1){
                int v = __hip_atomic_load(pollp, __ATOMIC_RELAXED, __HIP_MEMORY_SCOPE_AGENT);
                if (__all(v >= NS)) break;
                if (++spins > (1<<20)) break;
            }
            if (lane == 0)
                __hip_atomic_fetch_add(progp, 1, __ATOMIC_RELAXED, __HIP_MEMORY_SCOPE_AGENT);
        }
    }
}

__global__ void k_time(const float* __restrict__ xf, const float* __restrict__ W_time,
                       const float* __restrict__ b_time, float* __restrict__ out){
    int gw = (int)((blockIdx.x*(size_t)blockDim.x + threadIdx.x) >> 6);
    int lane = threadIdx.x & 63;
    if (gw >= NB*NS) return;
    const float* x = xf + (size_t)gw*NH;
    float s = 0.f;
    for (int k=lane;k<NH;k+=64) s += x[k]*W_time[k];
    for (int off=32; off; off>>=1) s += __shfl_down(s, off);
    if (lane == 0) out[gw] = s + b_time[0];
}

extern "C" void kernel_launch(void* const* d_in, const int* in_sizes, int n_in,
                              void* d_out, int out_size, void* d_ws, size_t ws_size,
                              hipStream_t stream){
    const float* src    = (const float*)d_in[0];
    const int*   lens   = (const int*)d_in[1];
    const int*   seq    = (const int*)d_in[2];
    const float* X      = (const float*)d_in[3];
    const float* A      = (const float*)d_in[4];
    const float* W_attn = (const float*)d_in[5];
    const float* a_attn = (const float*)d_in[6];
    const float* W_ih   = (const float*)d_in[7];
    const float* W_hh   = (const float*)d_in[8];
    const float* b_ih   = (const float*)d_in[9];
    const float* b_hh   = (const float*)d_in[10];
    const float* h0     = (const float*)d_in[11];
    const float* W_poi  = (const float*)d_in[12];
    const float* b_poi  = (const float*)d_in[13];
    const float* W_time = (const float*)d_in[14];
    const float* b_time = (const float*)d_in[15];
    const float* W_cat  = (const float*)d_in[16];
    const float* b_cat  = (const float*)d_in[17];

    char* ws = (char*)d_ws;
    float*          xf      = (float*)(ws + XF_OFF);
    unsigned short* xb      = (unsigned short*)(ws + XB_OFF);
    unsigned short* Whh_bf  = (unsigned short*)(ws + WHH_OFF);
    double*         wh1     = (double*)(ws + WH1_OFF);
    double*         wh2     = (double*)(ws + WH2_OFF);
    float*          alpha   = (float*)(ws + AL_OFF);
    int*            idx     = (int*)(ws + IDX_OFF);
    float*          gh0     = (float*)(ws + GH0_OFF);
    int*            ctrl    = (int*)(ws + CTRL_OFF);
    unsigned short* Wpoi_bf = (unsigned short*)(ws + WPOI_OFF);
    unsigned short* Wcat_bf = (unsigned short*)(ws + WCAT_OFF);

    int overlap = (ws_size >= (size_t)WS_NEED) ? 1 : 0;
    unsigned short* xb2 = (ws_size >= (size_t)WS_NEED2) ? (unsigned short*)(ws + XB2_OFF) : xb;

    char* ob = (char*)d_out;
    unsigned short* src_bf = (unsigned short*)(ob + 0);         // dead before C writes
    unsigned short* Wih_bf = (unsigned short*)(ob + 9437184);
    float* gi = overlap ? (float*)(ws + GI_OFF) : (float*)(ob + 16777216);

    float* out_poi  = (float*)d_out;
    float* out_time = (float*)d_out + (size_t)8192*8192;
    float* out_cat  = out_time + 8192;

    k_init<<<4096, 256, 0, stream>>>(ctrl, src, src_bf, W_ih, Wih_bf, W_hh, Whh_bf,
                                     W_poi, Wpoi_bf, W_cat, Wcat_bf,
                                     X, W_attn, a_attn, wh1, wh2, h0, W_hh, b_hh, gh0);

    k_ag<<<2816, 256, 0, stream>>>(src_bf, Wih_bf, b_ih, gi,
                                   seq, lens, A, wh1, wh2, alpha, idx);

    k_mega<<<NWG_LAUNCH, 512, 0, stream>>>(gi, Whh_bf, b_hh, alpha, idx, gh0, h0,
                                           xf, xb, xb2, ctrl, Wpoi_bf, b_poi, Wcat_bf, b_cat,
                                           out_poi, out_cat, overlap);

    k_time<<<2048, 256, 0, stream>>>(xf, W_time, b_time, out_time);
}